// Round 1
// 968.733 us; speedup vs baseline: 1.1385x; 1.1385x over previous
//
#include <hip/hip_runtime.h>
#include <math.h>

#define Nn 19
#define Dd 64
#define KE 16
#define DIN 80
#define Tt 1024
#define Bb 16
#define Gg (Bb*Tt)
#define ALPHAc 0.05f
#define HOPW 0.475f
#define LNEPS 1e-5f

#define AN_STRIDE 384            // floats per graph: transposed a_norm rows of 20
#define PE_STRIDE 304
#define WS_NEED ((size_t)Gg * (AN_STRIDE + PE_STRIDE) * 4)

__device__ __forceinline__ float softplusf(float x){
  return (x > 0.f) ? (x + log1pf(expf(-x))) : log1pf(expf(x));
}

__device__ __forceinline__ float wsum(float v){
  #pragma unroll
  for (int o = 32; o > 0; o >>= 1) v += __shfl_xor(v, o, 64);
  return v;
}

__device__ __forceinline__ float rlanef(float v, int l){
  return __int_as_float(__builtin_amdgcn_readlane(__float_as_int(v), l));
}

// intra-wave LDS ordering fence (compile barrier + wave_barrier, 0 instructions)
__device__ __forceinline__ void wsync(){
  __asm__ volatile("" ::: "memory");
  __builtin_amdgcn_wave_barrier();
  __asm__ volatile("" ::: "memory");
}

// ======================= kernel 1: gcn_norm + eigensolver =======================
// 4 waves/block, one graph per wave, per-wave LDS arena, no block barriers.
// fp32 Jacobi: (c,s) and the eigenvector accumulation were ALREADY fp32; the
// fp64 A-matrix only doubled LDS bank pressure (b64 = 2 banks/lane) and halved
// FMA rate (v_fma_f64 is half-rate on CDNA4). Af: 19x21 fp32 stride-21 — with
// fp32 elements both Jacobi phases land in the free <=2-way bank regime.
// Arena 4896 B -> 19584 B/block -> 8 blocks/CU -> 100% occupancy (was 57%).
#define ARENA_BYTES 4896
__global__ __launch_bounds__(256)
void eig_kernel(const float* __restrict__ adj,
                const float* __restrict__ ew_p, const float* __restrict__ eb_p,
                float* __restrict__ anW, float* __restrict__ peW)
{
  const int wid  = threadIdx.x >> 6;
  const int lane = threadIdx.x & 63;
  const int g    = blockIdx.x * 4 + wid;

  __shared__ __align__(16) char arenaAll[4 * ARENA_BYTES];
  char* arena = arenaAll + wid * ARENA_BYTES;
  float*  Af  = (float*) (arena);            // [19][21] fp32 (1596 B)
  float*  Vf  = (float*) (arena + 1600);     // [19][21] fp32 (1596 B)
  float*  adjS= (float*) (arena + 1600);     // [361] raw adj (overlaps Vf; dead before Vf init)
  float*  peB = (float*) (arena + 3200);     // [304] pe staging
  float*  wS  = (float*) (arena + 3200);     // [361] softplus weights (dead before peB use)
  float*  rsS = (float*) (arena + 4648);     // [19]
  float*  csS = (float*) (arena + 4728);     // [19]
  float*  cS  = (float*) (arena + 4808);     // [9]
  float*  sS  = (float*) (arena + 4848);     // [9]

  const float ew = ew_p[0], eb = eb_p[0];

  for (int idx = lane; idx < Nn*Nn; idx += 64)
    adjS[idx] = adj[(size_t)g*(Nn*Nn) + idx];
  wsync();

  for (int idx = lane; idx < Nn*Nn; idx += 64) {
    int i = idx / Nn, j = idx - i*Nn;
    float a = adjS[idx];
    wS[idx] = (a > 0.f) ? softplusf(a*ew + eb) : ((i == j) ? 1.f : 0.f);
  }
  if (lane < Nn) {
    float rs = 0.f;
    for (int j = 0; j < Nn; ++j) rs += adjS[lane*Nn + j];
    rsS[lane] = rsqrtf(fmaxf(rs, 1e-6f));
  }
  wsync();
  if (lane < Nn) {
    float cs = 0.f;
    for (int i = 0; i < Nn; ++i) cs += wS[i*Nn + lane];
    csS[lane] = (cs > 0.f) ? rsqrtf(fmaxf(cs, 1e-30f)) : 0.f;
  }
  wsync();
  // write TRANSPOSED normalized adjacency to ws: anW[g][j*20+i] = an[i][j]
  for (int idx = lane; idx < Nn*Nn; idx += 64) {
    int i = idx / Nn, j = idx - i*Nn;
    anW[(size_t)g*AN_STRIDE + j*20 + i] = csS[i]*wS[idx]*csS[j];
  }
  // symmetrized Laplacian (fp32), stride 21; pads zeroed
  for (int idx = lane; idx < Nn*Nn; idx += 64) {
    int i = idx / Nn, j = idx - i*Nn;
    float anij = rsS[i]*adjS[i*Nn + j]*rsS[j];
    float anji = rsS[j]*adjS[j*Nn + i]*rsS[i];
    Af[i*21 + j] = ((i == j) ? (1.f + 1e-5f) : 0.f) - 0.5f*(anij + anji);
  }
  if (lane < Nn) { Af[lane*21 + 19] = 0.f; Af[lane*21 + 20] = 0.f; }
  wsync();
  for (int idx = lane; idx < Nn*21; idx += 64) {
    int i = idx / 21;
    Vf[idx] = (idx == i*22) ? 1.f : 0.f;
  }
  wsync();

  // per-lane pair state (round-robin with bye). items: (k,i), k<19, i in 1..9
  int aR[3], bR[3], kR[3], k21R[3], iR0[3];
  #pragma unroll
  for (int it = 0; it < 3; ++it) {
    int item = lane + it*64;
    int k = item / 9, i0 = item - k*9;          // i0 in 0..8 -> pair i0+1
    kR[it] = k; k21R[it] = k*21; iR0[it] = i0;
    aR[it] = i0 + 1;                            // (r=0 + i)
    bR[it] = 18 - i0;                           // (r=0 + 19 - i) mod 19
  }
  int aA = lane + 1, bA = 18 - lane;            // angle lanes (lane<9 -> pair i=lane+1)

  for (int sweep = 0; sweep < 14; ++sweep) {
    if (sweep) {
      // fp32-safe convergence test: sum ONLY off-diagonal squares (the old
      // "total - diag" form cancels catastrophically in fp32: eps*||A||^2 >> thr)
      float off = 0.f;
      for (int idx = lane; idx < Nn*21; idx += 64) {
        int i = idx / 21;
        float v = Af[idx];
        off += (idx != i*22) ? v*v : 0.f;
      }
      off = wsum(off);
      if (off < 1e-9f) break;
    }

    for (int r = 0; r < Nn; ++r) {
      bool active = false;
      if (lane < 9) {
        int p = min(aA, bA), q = max(aA, bA);
        float apq = Af[p*21 + q];
        float c = 1.f, s = 0.f;
        if (fabsf(apq) > 1e-12f) {
          float app = Af[p*22], aqq = Af[q*22];
          float tau = (aqq - app) / (2.f*apq);
          float tt  = sqrtf(1.f + tau*tau);
          float tv  = (tau >= 0.f) ? 1.f/(tau + tt) : 1.f/(tau - tt);
          c = rsqrtf(1.f + tv*tv);
          s = tv*c;
          active = true;
        }
        cS[lane] = c; sS[lane] = s;
      }
      int anyact = __any(active);
      wsync();

      if (anyact) {
        float cI[3], sI[3]; int pI[3], qI[3];
        #pragma unroll
        for (int it = 0; it < 3; ++it) {
          cI[it] = cS[iR0[it]]; sI[it] = sS[iR0[it]];
          pI[it] = min(aR[it], bR[it]); qI[it] = max(aR[it], bR[it]);
        }
        // phase A: A <- A*J (columns), V <- V*J
        #pragma unroll
        for (int it = 0; it < 3; ++it) {
          if (lane + it*64 < 171) {
            int p = pI[it], q = qI[it], base = k21R[it];
            float c = cI[it], s = sI[it];
            float akp = Af[base + p], akq = Af[base + q];
            Af[base + p] = c*akp - s*akq;
            Af[base + q] = s*akp + c*akq;
            float vkp = Vf[base + p], vkq = Vf[base + q];
            Vf[base + p] = c*vkp - s*vkq;
            Vf[base + q] = s*vkp + c*vkq;
          }
        }
        wsync();
        // phase B: A <- J^T*A (rows)
        #pragma unroll
        for (int it = 0; it < 3; ++it) {
          if (lane + it*64 < 171) {
            int p21 = pI[it]*21, q21 = qI[it]*21, k = kR[it];
            float c = cI[it], s = sI[it];
            float arp = Af[p21 + k], arq = Af[q21 + k];
            Af[p21 + k] = c*arp - s*arq;
            Af[q21 + k] = s*arp + c*arq;
          }
        }
        wsync();
      }

      // increment pair state: a,b += 1 (mod 19)
      #pragma unroll
      for (int it = 0; it < 3; ++it) {
        int t1 = aR[it] + 1; aR[it] = (t1 >= 19) ? t1 - 19 : t1;
        int t2 = bR[it] + 1; bR[it] = (t2 >= 19) ? t2 - 19 : t2;
      }
      { int t1 = aA + 1; aA = (t1 >= 19) ? t1 - 19 : t1;
        int t2 = bA + 1; bA = (t2 >= 19) ? t2 - 19 : t2; }
    }
  }

  // rank eigenvalues, sign-fix, stage pe, write out
  if (lane < Nn) {
    float lam = Af[lane*22];
    int rk = 0;
    for (int j = 0; j < Nn; ++j) {
      float lj = Af[j*22];
      rk += (lj < lam) || (lj == lam && j < lane);
    }
    if (rk < KE) {
      float sacc = 0.f;
      for (int n = 0; n < Nn; ++n) sacc += Vf[n*21 + lane];
      float sgn = (sacc < 0.f) ? -1.f : 1.f;
      for (int n = 0; n < Nn; ++n) peB[n*KE + rk] = Vf[n*21 + lane]*sgn;
    }
  }
  wsync();
  for (int idx = lane; idx < Nn*KE; idx += 64)
    peW[(size_t)g*PE_STRIDE + idx] = peB[idx];
}

// ======================= kernel 2: SSGConv x2 + LN (LDS-free) =======================
__global__ __launch_bounds__(64)
void gnn_kernel(const float* __restrict__ feat,
                const float* __restrict__ anW, const float* __restrict__ peW,
                const float* __restrict__ W0, const float* __restrict__ b0,
                const float* __restrict__ W1, const float* __restrict__ b1,
                const float* __restrict__ g0, const float* __restrict__ be0,
                const float* __restrict__ g1, const float* __restrict__ be1,
                float* __restrict__ out)
{
  const int g = blockIdx.x, lane = threadIdx.x;
  const int b = g >> 10, t = g & (Tt - 1);

  const float* an = anW + (size_t)g*AN_STRIDE;   // wave-uniform rows (transposed a_norm)

  float xa[Nn], xb[Nn];
  const float* fb = feat + (((size_t)b*Nn)*Tt + t)*Dd + lane;
  #pragma unroll
  for (int n = 0; n < Nn; ++n) xa[n] = fb[(size_t)n*Tt*Dd];
  #pragma unroll
  for (int n = 0; n < Nn; ++n)
    xb[n] = (lane < KE) ? peW[(size_t)g*PE_STRIDE + n*KE + lane] : 0.f;

  // ---- layer0 hop1 ----
  float x1a[Nn], x1b[Nn];
  for (int j = 0; j < Nn; ++j) {
    float aa = 0.f, ab = 0.f;
    #pragma unroll
    for (int i = 0; i < Nn; ++i) {
      float av = an[j*20 + i];
      aa = fmaf(av, xa[i], aa);
      ab = fmaf(av, xb[i], ab);
    }
    x1a[j] = aa; x1b[j] = ab;
  }
  float h0a[Nn], h0b[Nn];
  #pragma unroll
  for (int n = 0; n < Nn; ++n) {
    h0a[n] = ALPHAc*xa[n] + HOPW*x1a[n];
    h0b[n] = ALPHAc*xb[n] + HOPW*x1b[n];
  }
  // ---- layer0 hop2 ----
  for (int j = 0; j < Nn; ++j) {
    float aa = 0.f, ab = 0.f;
    #pragma unroll
    for (int i = 0; i < Nn; ++i) {
      float av = an[j*20 + i];
      aa = fmaf(av, x1a[i], aa);
      ab = fmaf(av, x1b[i], ab);
    }
    h0a[j] += HOPW*aa;
    h0b[j] += HOPW*ab;
  }

  // ---- matmul0 (readlane broadcast of h columns) + LN0 ----
  float acc[Nn];
  #pragma unroll
  for (int n = 0; n < Nn; ++n) acc[n] = 0.f;
  {
    const float* w0p = W0 + lane*DIN;
    #pragma unroll
    for (int kb = 0; kb < 64; kb += 16) {
      float w[16];
      #pragma unroll
      for (int q4 = 0; q4 < 4; ++q4)
        *(float4*)&w[4*q4] = *(const float4*)(w0p + kb + 4*q4);
      #pragma unroll
      for (int kk = 0; kk < 16; ++kk) {
        int k = kb + kk;
        #pragma unroll
        for (int n = 0; n < Nn; ++n)
          acc[n] = fmaf(rlanef(h0a[n], k), w[kk], acc[n]);
      }
    }
    float w[16];
    #pragma unroll
    for (int q4 = 0; q4 < 4; ++q4)
      *(float4*)&w[4*q4] = *(const float4*)(w0p + 64 + 4*q4);
    #pragma unroll
    for (int kk = 0; kk < 16; ++kk) {
      #pragma unroll
      for (int n = 0; n < Nn; ++n)
        acc[n] = fmaf(rlanef(h0b[n], kk), w[kk], acc[n]);
    }
  }
  float yv[Nn];
  {
    float bias = b0[lane], gam = g0[lane], bet = be0[lane];
    #pragma unroll
    for (int n = 0; n < Nn; ++n) {
      float v  = acc[n] + bias;
      float mu = wsum(v)*(1.f/64.f);
      float d  = v - mu;
      float var = wsum(d*d)*(1.f/64.f);
      yv[n] = d*rsqrtf(var + LNEPS)*gam + bet;
    }
  }

  // ---- layer1 hops ----
  float x1c[Nn];
  for (int j = 0; j < Nn; ++j) {
    float aa = 0.f;
    #pragma unroll
    for (int i = 0; i < Nn; ++i)
      aa = fmaf(an[j*20 + i], yv[i], aa);
    x1c[j] = aa;
  }
  float h1[Nn];
  #pragma unroll
  for (int n = 0; n < Nn; ++n) h1[n] = ALPHAc*yv[n] + HOPW*x1c[n];
  for (int j = 0; j < Nn; ++j) {
    float aa = 0.f;
    #pragma unroll
    for (int i = 0; i < Nn; ++i)
      aa = fmaf(an[j*20 + i], x1c[i], aa);
    h1[j] += HOPW*aa;
  }

  // ---- matmul1 + residual + LN1 + store ----
  float acc1[Nn];
  #pragma unroll
  for (int n = 0; n < Nn; ++n) acc1[n] = 0.f;
  {
    const float* w1p = W1 + lane*Dd;
    #pragma unroll
    for (int kb = 0; kb < 64; kb += 16) {
      float w[16];
      #pragma unroll
      for (int q4 = 0; q4 < 4; ++q4)
        *(float4*)&w[4*q4] = *(const float4*)(w1p + kb + 4*q4);
      #pragma unroll
      for (int kk = 0; kk < 16; ++kk) {
        int k = kb + kk;
        #pragma unroll
        for (int n = 0; n < Nn; ++n)
          acc1[n] = fmaf(rlanef(h1[n], k), w[kk], acc1[n]);
      }
    }
  }
  {
    float bias = b1[lane], gam = g1[lane], bet = be1[lane];
    float* ob = out + (((size_t)b*Nn)*Tt + t)*Dd + lane;
    #pragma unroll
    for (int n = 0; n < Nn; ++n) {
      float v  = acc1[n] + bias + yv[n];
      float mu = wsum(v)*(1.f/64.f);
      float d  = v - mu;
      float var = wsum(d*d)*(1.f/64.f);
      ob[(size_t)n*Tt*Dd] = d*rsqrtf(var + LNEPS)*gam + bet;
    }
  }
}

// ======================= fallback: monolithic kernel (round-1, known-correct) =======================
__global__ __launch_bounds__(64)
void gcm_mono(
  const float* __restrict__ feat,
  const float* __restrict__ adj,
  const float* __restrict__ ew_p, const float* __restrict__ eb_p,
  const float* __restrict__ W0, const float* __restrict__ b0,
  const float* __restrict__ W1, const float* __restrict__ b1,
  const float* __restrict__ g0, const float* __restrict__ be0,
  const float* __restrict__ g1, const float* __restrict__ be1,
  float* __restrict__ out)
{
  const int g    = blockIdx.x;
  const int lane = threadIdx.x;
  const int b    = g >> 10;
  const int t    = g & (Tt - 1);

  __shared__ float  anS[Nn*Nn];
  __shared__ float  peS[Nn*KE];
  __shared__ double evS[Nn];
  __shared__ float  rsS[Nn];
  __shared__ float  csS[Nn];
  __shared__ __align__(16) char arena[6080];
  double* Ad   = (double*)(arena);
  float*  Vf   = (float*)(arena + 3040);
  float*  adjS = (float*)(arena + 4560);
  float*  hb   = (float*)(arena);

  float xr[Nn];
  const float* fb = feat + (((size_t)b*Nn)*Tt + t)*Dd + lane;
  #pragma unroll
  for (int n = 0; n < Nn; ++n) xr[n] = fb[(size_t)n*Tt*Dd];

  const float ew = ew_p[0], eb = eb_p[0];

  for (int idx = lane; idx < Nn*Nn; idx += 64)
    adjS[idx] = adj[(size_t)g*(Nn*Nn) + idx];
  __syncthreads();

  if (lane < Nn) {
    float rs = 0.f;
    for (int j = 0; j < Nn; ++j) rs += adjS[lane*Nn + j];
    rsS[lane] = rsqrtf(fmaxf(rs, 1e-6f));
  }
  for (int idx = lane; idx < Nn*Nn; idx += 64) {
    int i = idx / Nn, j = idx - i*Nn;
    float a = adjS[idx];
    bool m = a > 0.f;
    float wv = m ? softplusf(a*ew + eb) : ((i == j) ? 1.f : 0.f);
    anS[idx] = wv;
  }
  __syncthreads();
  if (lane < Nn) {
    float cs = 0.f;
    for (int i = 0; i < Nn; ++i) cs += anS[i*Nn + lane];
    csS[lane] = (cs > 0.f) ? rsqrtf(fmaxf(cs, 1e-30f)) : 0.f;
  }
  __syncthreads();
  for (int idx = lane; idx < Nn*Nn; idx += 64) {
    int i = idx / Nn, j = idx - i*Nn;
    anS[idx] = csS[i]*anS[idx]*csS[j];
    float anij = rsS[i]*adjS[i*Nn + j]*rsS[j];
    float anji = rsS[j]*adjS[j*Nn + i]*rsS[i];
    double m = ((i == j) ? (1.0 + 1e-5) : 0.0) - 0.5*((double)anij + (double)anji);
    Ad[i*20 + j] = m;
    Vf[i*20 + j] = (i == j) ? 1.f : 0.f;
  }
  __syncthreads();

  for (int sweep = 0; sweep < 30; ++sweep) {
    double off = 0.0;
    for (int idx = lane; idx < Nn*Nn; idx += 64) {
      int i = idx / Nn, j = idx - i*Nn;
      if (i < j) { double v = Ad[i*20 + j]; off += v*v; }
    }
    #pragma unroll
    for (int o = 32; o > 0; o >>= 1) off += __shfl_xor(off, o, 64);
    if (off < 1e-22) break;
    for (int p = 0; p < Nn - 1; ++p) {
      for (int q = p + 1; q < Nn; ++q) {
        double apq = Ad[p*20 + q];
        if (fabs(apq) > 1e-15) {
          double app = Ad[p*20 + p], aqq = Ad[q*20 + q];
          double tau = (aqq - app) / (2.0*apq);
          double tt  = sqrt(1.0 + tau*tau);
          double tv  = (tau >= 0.0) ? 1.0/(tau + tt) : 1.0/(tau - tt);
          double c   = 1.0/sqrt(1.0 + tv*tv);
          double s   = tv*c;
          double akp = 0.0, akq = 0.0; float vkp = 0.f, vkq = 0.f;
          if (lane < Nn) {
            akp = Ad[lane*20 + p]; akq = Ad[lane*20 + q];
            vkp = Vf[lane*20 + p]; vkq = Vf[lane*20 + q];
          }
          __syncthreads();
          if (lane < Nn) {
            double nkp = c*akp - s*akq;
            double nkq = s*akp + c*akq;
            if (lane == p) {
              nkp = c*c*app - 2.0*c*s*apq + s*s*aqq;
              nkq = 0.0;
            } else if (lane == q) {
              nkp = 0.0;
              nkq = s*s*app + 2.0*c*s*apq + c*c*aqq;
            }
            Ad[lane*20 + p] = nkp; Ad[p*20 + lane] = nkp;
            Ad[lane*20 + q] = nkq; Ad[q*20 + lane] = nkq;
            float fc = (float)c, fs = (float)s;
            Vf[lane*20 + p] = fc*vkp - fs*vkq;
            Vf[lane*20 + q] = fs*vkp + fc*vkq;
          }
          __syncthreads();
        }
      }
    }
  }

  if (lane < Nn) evS[lane] = Ad[lane*20 + lane];
  __syncthreads();
  if (lane < Nn) {
    double lam = evS[lane];
    int r = 0;
    for (int j = 0; j < Nn; ++j) {
      double lj = evS[j];
      r += (lj < lam) || (lj == lam && j < lane);
    }
    if (r < KE) {
      float sacc = 0.f;
      for (int n = 0; n < Nn; ++n) sacc += Vf[n*20 + lane];
      float sgn = (sacc < 0.f) ? -1.f : 1.f;
      for (int n = 0; n < Nn; ++n) peS[n*KE + r] = Vf[n*20 + lane]*sgn;
    }
  }
  __syncthreads();

  {
    float x1[Nn], x2[Nn];
    for (int j = 0; j < Nn; ++j) {
      float a2 = 0.f;
      #pragma unroll
      for (int i = 0; i < Nn; ++i) a2 += anS[i*Nn + j]*xr[i];
      x1[j] = a2;
    }
    for (int j = 0; j < Nn; ++j) {
      float a2 = 0.f;
      #pragma unroll
      for (int i = 0; i < Nn; ++i) a2 += anS[i*Nn + j]*x1[i];
      x2[j] = a2;
    }
    #pragma unroll
    for (int n = 0; n < Nn; ++n)
      hb[n*DIN + lane] = ALPHAc*xr[n] + HOPW*(x1[n] + x2[n]);
  }
  if (lane < KE) {
    float xc[Nn], x1[Nn], x2[Nn];
    #pragma unroll
    for (int n = 0; n < Nn; ++n) xc[n] = peS[n*KE + lane];
    for (int j = 0; j < Nn; ++j) {
      float a2 = 0.f;
      #pragma unroll
      for (int i = 0; i < Nn; ++i) a2 += anS[i*Nn + j]*xc[i];
      x1[j] = a2;
    }
    for (int j = 0; j < Nn; ++j) {
      float a2 = 0.f;
      #pragma unroll
      for (int i = 0; i < Nn; ++i) a2 += anS[i*Nn + j]*x1[i];
      x2[j] = a2;
    }
    #pragma unroll
    for (int n = 0; n < Nn; ++n)
      hb[n*DIN + Dd + lane] = ALPHAc*xc[n] + HOPW*(x1[n] + x2[n]);
  }
  __syncthreads();

  float acc[Nn];
  #pragma unroll
  for (int n = 0; n < Nn; ++n) acc[n] = 0.f;
  {
    const float* w0r = W0 + lane*DIN;
    #pragma unroll 8
    for (int k = 0; k < DIN; ++k) {
      float wv = w0r[k];
      #pragma unroll
      for (int n = 0; n < Nn; ++n) acc[n] += hb[n*DIN + k]*wv;
    }
  }
  float yv[Nn];
  {
    float bias = b0[lane], gam = g0[lane], bet = be0[lane];
    #pragma unroll
    for (int n = 0; n < Nn; ++n) {
      float v  = acc[n] + bias;
      float mu = wsum(v)*(1.f/64.f);
      float d  = v - mu;
      float var = wsum(d*d)*(1.f/64.f);
      yv[n] = d*rsqrtf(var + LNEPS)*gam + bet;
    }
  }

  {
    float x1[Nn], x2[Nn];
    for (int j = 0; j < Nn; ++j) {
      float a2 = 0.f;
      #pragma unroll
      for (int i = 0; i < Nn; ++i) a2 += anS[i*Nn + j]*yv[i];
      x1[j] = a2;
    }
    for (int j = 0; j < Nn; ++j) {
      float a2 = 0.f;
      #pragma unroll
      for (int i = 0; i < Nn; ++i) a2 += anS[i*Nn + j]*x1[i];
      x2[j] = a2;
    }
    __syncthreads();
    #pragma unroll
    for (int n = 0; n < Nn; ++n)
      hb[n*Dd + lane] = ALPHAc*yv[n] + HOPW*(x1[n] + x2[n]);
    __syncthreads();
  }

  float acc1[Nn];
  #pragma unroll
  for (int n = 0; n < Nn; ++n) acc1[n] = 0.f;
  {
    const float* w1r = W1 + lane*Dd;
    #pragma unroll 8
    for (int k = 0; k < Dd; ++k) {
      float wv = w1r[k];
      #pragma unroll
      for (int n = 0; n < Nn; ++n) acc1[n] += hb[n*Dd + k]*wv;
    }
  }
  {
    float bias = b1[lane], gam = g1[lane], bet = be1[lane];
    float* ob = out + (((size_t)b*Nn)*Tt + t)*Dd + lane;
    #pragma unroll
    for (int n = 0; n < Nn; ++n) {
      float v  = acc1[n] + bias + yv[n];
      float mu = wsum(v)*(1.f/64.f);
      float d  = v - mu;
      float var = wsum(d*d)*(1.f/64.f);
      ob[(size_t)n*Tt*Dd] = d*rsqrtf(var + LNEPS)*gam + bet;
    }
  }
}

extern "C" void kernel_launch(void* const* d_in, const int* in_sizes, int n_in,
                              void* d_out, int out_size, void* d_ws, size_t ws_size,
                              hipStream_t stream) {
  (void)in_sizes; (void)n_in; (void)out_size;
  const float* feat = (const float*)d_in[0];
  const float* adj  = (const float*)d_in[1];
  const float* ew   = (const float*)d_in[2];
  const float* eb   = (const float*)d_in[3];
  const float* W0   = (const float*)d_in[4];
  const float* b0   = (const float*)d_in[5];
  const float* W1   = (const float*)d_in[6];
  const float* b1   = (const float*)d_in[7];
  const float* g0   = (const float*)d_in[8];
  const float* be0  = (const float*)d_in[9];
  const float* g1   = (const float*)d_in[10];
  const float* be1  = (const float*)d_in[11];
  float* out = (float*)d_out;

  if (ws_size >= WS_NEED) {
    float* anW = (float*)d_ws;
    float* peW = anW + (size_t)Gg*AN_STRIDE;
    hipLaunchKernelGGL(eig_kernel, dim3(Gg/4), dim3(256), 0, stream,
                       adj, ew, eb, anW, peW);
    hipLaunchKernelGGL(gnn_kernel, dim3(Gg), dim3(64), 0, stream,
                       feat, anW, peW, W0, b0, W1, b1, g0, be0, g1, be1, out);
  } else {
    hipLaunchKernelGGL(gcm_mono, dim3(Gg), dim3(64), 0, stream,
                       feat, adj, ew, eb, W0, b0, W1, b1, g0, be0, g1, be1, out);
  }
}

// Round 2
// 790.337 us; speedup vs baseline: 1.3955x; 1.2257x over previous
//
#include <hip/hip_runtime.h>
#include <math.h>

#define Nn 19
#define Dd 64
#define KE 16
#define DIN 80
#define Tt 1024
#define Bb 16
#define Gg (Bb*Tt)
#define ALPHAc 0.05f
#define HOPW 0.475f
#define LNEPS 1e-5f

#define AN_STRIDE 384            // floats per graph: transposed a_norm rows of 20
#define PE_STRIDE 304
#define WS_NEED ((size_t)Gg * (AN_STRIDE + PE_STRIDE) * 4)

__device__ __forceinline__ float softplusf(float x){
  return (x > 0.f) ? (x + log1pf(expf(-x))) : log1pf(expf(x));
}

__device__ __forceinline__ float wsum(float v){
  #pragma unroll
  for (int o = 32; o > 0; o >>= 1) v += __shfl_xor(v, o, 64);
  return v;
}

__device__ __forceinline__ float rlanef(float v, int l){
  return __int_as_float(__builtin_amdgcn_readlane(__float_as_int(v), l));
}

// intra-wave LDS ordering fence (compile barrier + wave_barrier, 0 instructions)
__device__ __forceinline__ void wsync(){
  __asm__ volatile("" ::: "memory");
  __builtin_amdgcn_wave_barrier();
  __asm__ volatile("" ::: "memory");
}

// ======================= kernel 1: gcn_norm + eigensolver =======================
// 4 waves/block, one graph per wave, per-wave LDS arena, no block barriers.
// FUSED SYMMETRIC Jacobi round: A <- J^T A J decomposed into independent 2x2
// blocks over the upper triangle only (36 pair-pair + 9 diag + 9 bye blocks =
// 54 lanes, ONE pass, 378 LDS element-ops vs 1368 for the split-phase version).
// V stored COLUMN-major (stride 20) so the column rotation V <- V*J runs as
// float4/b128 LDS ops (9 pairs x 5 row-chunks = 45 lanes x 4 b128 instrs).
// (c,s) packed float2 -> single b64 broadcast read per pair.
#define ARENA_BYTES 4832
__global__ __launch_bounds__(256)
void eig_kernel(const float* __restrict__ adj,
                const float* __restrict__ ew_p, const float* __restrict__ eb_p,
                float* __restrict__ anW, float* __restrict__ peW)
{
  const int wid  = threadIdx.x >> 6;
  const int lane = threadIdx.x & 63;
  const int g    = blockIdx.x * 4 + wid;

  __shared__ __align__(16) char arenaAll[4 * ARENA_BYTES];
  char* arena = arenaAll + wid * ARENA_BYTES;
  float*  Af  = (float*) (arena);            // [19][21] fp32; canonical UPPER maintained (1596 B)
  float*  Vf  = (float*) (arena + 1600);     // [19 cols][20] col-major fp32 (1520 B)
  float*  adjS= (float*) (arena + 1600);     // [361] raw adj (overlaps Vf; dead before Vf init)
  float*  peB = (float*) (arena + 3136);     // [304] pe staging
  float*  wS  = (float*) (arena + 3136);     // [361] softplus weights (dead before peB use)
  float*  rsS = (float*) (arena + 4592);     // [19]
  float*  csS = (float*) (arena + 4672);     // [19]
  float2* cs2 = (float2*)(arena + 4752);     // [9] packed (c,s)

  const float ew = ew_p[0], eb = eb_p[0];

  for (int idx = lane; idx < Nn*Nn; idx += 64)
    adjS[idx] = adj[(size_t)g*(Nn*Nn) + idx];
  wsync();

  for (int idx = lane; idx < Nn*Nn; idx += 64) {
    int i = idx / Nn, j = idx - i*Nn;
    float a = adjS[idx];
    wS[idx] = (a > 0.f) ? softplusf(a*ew + eb) : ((i == j) ? 1.f : 0.f);
  }
  if (lane < Nn) {
    float rs = 0.f;
    for (int j = 0; j < Nn; ++j) rs += adjS[lane*Nn + j];
    rsS[lane] = rsqrtf(fmaxf(rs, 1e-6f));
  }
  wsync();
  if (lane < Nn) {
    float cs = 0.f;
    for (int i = 0; i < Nn; ++i) cs += wS[i*Nn + lane];
    csS[lane] = (cs > 0.f) ? rsqrtf(fmaxf(cs, 1e-30f)) : 0.f;
  }
  wsync();
  // write TRANSPOSED normalized adjacency to ws: anW[g][j*20+i] = an[i][j]
  for (int idx = lane; idx < Nn*Nn; idx += 64) {
    int i = idx / Nn, j = idx - i*Nn;
    anW[(size_t)g*AN_STRIDE + j*20 + i] = csS[i]*wS[idx]*csS[j];
  }
  // symmetrized Laplacian (fp32), stride 21; pads zeroed
  for (int idx = lane; idx < Nn*Nn; idx += 64) {
    int i = idx / Nn, j = idx - i*Nn;
    float anij = rsS[i]*adjS[i*Nn + j]*rsS[j];
    float anji = rsS[j]*adjS[j*Nn + i]*rsS[i];
    Af[i*21 + j] = ((i == j) ? (1.f + 1e-5f) : 0.f) - 0.5f*(anij + anji);
  }
  if (lane < Nn) { Af[lane*21 + 19] = 0.f; Af[lane*21 + 20] = 0.f; }
  wsync();
  // V = I, column-major stride 20 (pad row 19 zeroed)
  for (int idx = lane; idx < Nn*20; idx += 64) {
    int c = idx / 20, r2 = idx - c*20;
    Vf[idx] = (r2 == c) ? 1.f : 0.f;
  }
  wsync();

  // ---- static per-lane roles ----
  // lanes 0..35 : off-diag blocks (li<lj), triangular mapping
  // lanes 36..44: diag blocks (li==lj==lane-36) -- unified generic code path
  // lanes 45..53: bye blocks, pair li=lane-45
  // lanes 0..44 : ALSO V-chunks: pair jv=lane%9, row-chunk (lane/9)*4
  int li = 0, lj = 0;
  if (lane < 36) {
    int l = lane, row = 0, cnt = 8;
    while (l >= cnt) { l -= cnt; ++row; --cnt; }
    li = row; lj = row + 1 + l;
  } else if (lane < 45) {
    li = lj = lane - 36;
  } else if (lane < 54) {
    li = lane - 45; lj = 0;
  }
  // round-robin pair state: pair t at global round R is ((t+1+R)%19, (18-t+R)%19)
  int ai = li + 1, bi = 18 - li;
  int aj = lj + 1, bj = 18 - lj;
  const int jv = lane % 9;                 // V pair index (lanes < 45)
  int av = jv + 1, bv = 18 - jv;
  const int mrow = (lane / 9) * 4;         // V row-chunk start (0,4,8,12,16)
  int rr = 0;                              // global round counter mod 19 (= bye index)

  for (int sweep = 0; sweep < 14; ++sweep) {
    if (sweep) {
      // upper-triangle-only off^2 (lower triangle is stale by design)
      float off = 0.f;
      for (int idx = lane; idx < Nn*21; idx += 64) {
        int i2 = idx / 21, j2 = idx - i2*21;
        float v = Af[idx];
        off += (j2 > i2 && j2 < Nn) ? v*v : 0.f;
      }
      off = wsum(off);
      if (off < 5e-10f) break;
    }

    for (int r = 0; r < Nn; ++r) {
      bool active = false;
      if (lane < 9) {
        int a = rr + 1 + lane;  if (a >= 19) a -= 19;
        int b = rr + 18 - lane; if (b >= 19) b -= 19;
        int p = min(a, b), q = max(a, b);
        float apq = Af[p*21 + q];
        float c = 1.f, s = 0.f;
        if (fabsf(apq) > 1e-12f) {
          float app = Af[p*22], aqq = Af[q*22];
          float tau = (aqq - app) / (2.f*apq);
          float tt  = sqrtf(1.f + tau*tau);
          float tv  = (tau >= 0.f) ? 1.f/(tau + tt) : 1.f/(tau - tt);
          c = rsqrtf(1.f + tv*tv);
          s = tv*c;
          active = true;
        }
        cs2[lane] = make_float2(c, s);
      }
      int anyact = __any(active);
      wsync();

      if (anyact) {
        // ---- unified 2x2 block update on canonical upper triangle ----
        if (lane < 45) {
          int pi = min(ai, bi), qi = max(ai, bi);
          int pj = min(aj, bj), qj = max(aj, bj);
          float2 csi = cs2[li], csj = cs2[lj];
          int a00 = (pi < pj) ? pi*21 + pj : pj*21 + pi;
          int a01 = (pi < qj) ? pi*21 + qj : qj*21 + pi;
          int a10 = (qi < pj) ? qi*21 + pj : pj*21 + qi;
          int a11 = (qi < qj) ? qi*21 + qj : qj*21 + qi;
          float App = Af[a00], Apq = Af[a01], Aqp = Af[a10], Aqq = Af[a11];
          // column rotation j
          float B0 = csj.x*App - csj.y*Apq;
          float B1 = csj.y*App + csj.x*Apq;
          float B2 = csj.x*Aqp - csj.y*Aqq;
          float B3 = csj.y*Aqp + csj.x*Aqq;
          // row rotation i (for diag lanes a01==a10: second write wins, ~0)
          Af[a00] = csi.x*B0 - csi.y*B2;
          Af[a01] = csi.x*B1 - csi.y*B3;
          Af[a10] = csi.y*B0 + csi.x*B2;
          Af[a11] = csi.y*B1 + csi.x*B3;
        } else if (lane < 54) {
          // bye row (index rr) x pair li: one-sided rotation
          int p = min(ai, bi), q = max(ai, bi);
          float2 cs = cs2[li];
          int b = rr;
          int e0 = (b < p) ? b*21 + p : p*21 + b;
          int e1 = (b < q) ? b*21 + q : q*21 + b;
          float ep = Af[e0], eq = Af[e1];
          Af[e0] = cs.x*ep - cs.y*eq;
          Af[e1] = cs.y*ep + cs.x*eq;
        }
        // ---- V column rotation, 4 rows per lane via b128 ----
        if (lane < 45) {
          int pv = min(av, bv), qv = max(av, bv);
          float2 cs = cs2[jv];
          float4 vp = *(const float4*)(Vf + pv*20 + mrow);
          float4 vq = *(const float4*)(Vf + qv*20 + mrow);
          float4 np, nq;
          np.x = cs.x*vp.x - cs.y*vq.x;  nq.x = cs.y*vp.x + cs.x*vq.x;
          np.y = cs.x*vp.y - cs.y*vq.y;  nq.y = cs.y*vp.y + cs.x*vq.y;
          np.z = cs.x*vp.z - cs.y*vq.z;  nq.z = cs.y*vp.z + cs.x*vq.z;
          np.w = cs.x*vp.w - cs.y*vq.w;  nq.w = cs.y*vp.w + cs.x*vq.w;
          *(float4*)(Vf + pv*20 + mrow) = np;
          *(float4*)(Vf + qv*20 + mrow) = nq;
        }
        wsync();
      }

      // advance round-robin state (unconditional, persists across sweeps)
      ++ai; if (ai >= 19) ai = 0;
      ++bi; if (bi >= 19) bi = 0;
      ++aj; if (aj >= 19) aj = 0;
      ++bj; if (bj >= 19) bj = 0;
      ++av; if (av >= 19) av = 0;
      ++bv; if (bv >= 19) bv = 0;
      ++rr; if (rr >= 19) rr = 0;
    }
  }

  // rank eigenvalues, sign-fix, stage pe, write out (V is column-major now)
  if (lane < Nn) {
    float lam = Af[lane*22];
    int rk = 0;
    for (int j = 0; j < Nn; ++j) {
      float lj2 = Af[j*22];
      rk += (lj2 < lam) || (lj2 == lam && j < lane);
    }
    if (rk < KE) {
      float sacc = 0.f;
      for (int n = 0; n < Nn; ++n) sacc += Vf[lane*20 + n];
      float sgn = (sacc < 0.f) ? -1.f : 1.f;
      for (int n = 0; n < Nn; ++n) peB[n*KE + rk] = Vf[lane*20 + n]*sgn;
    }
  }
  wsync();
  for (int idx = lane; idx < Nn*KE; idx += 64)
    peW[(size_t)g*PE_STRIDE + idx] = peB[idx];
}

// ======================= kernel 2: SSGConv x2 + LN (LDS-free) =======================
__global__ __launch_bounds__(64)
void gnn_kernel(const float* __restrict__ feat,
                const float* __restrict__ anW, const float* __restrict__ peW,
                const float* __restrict__ W0, const float* __restrict__ b0,
                const float* __restrict__ W1, const float* __restrict__ b1,
                const float* __restrict__ g0, const float* __restrict__ be0,
                const float* __restrict__ g1, const float* __restrict__ be1,
                float* __restrict__ out)
{
  const int g = blockIdx.x, lane = threadIdx.x;
  const int b = g >> 10, t = g & (Tt - 1);

  const float* an = anW + (size_t)g*AN_STRIDE;   // wave-uniform rows (transposed a_norm)

  float xa[Nn], xb[Nn];
  const float* fb = feat + (((size_t)b*Nn)*Tt + t)*Dd + lane;
  #pragma unroll
  for (int n = 0; n < Nn; ++n) xa[n] = fb[(size_t)n*Tt*Dd];
  #pragma unroll
  for (int n = 0; n < Nn; ++n)
    xb[n] = (lane < KE) ? peW[(size_t)g*PE_STRIDE + n*KE + lane] : 0.f;

  // ---- layer0 hop1 ----
  float x1a[Nn], x1b[Nn];
  for (int j = 0; j < Nn; ++j) {
    float aa = 0.f, ab = 0.f;
    #pragma unroll
    for (int i = 0; i < Nn; ++i) {
      float av = an[j*20 + i];
      aa = fmaf(av, xa[i], aa);
      ab = fmaf(av, xb[i], ab);
    }
    x1a[j] = aa; x1b[j] = ab;
  }
  float h0a[Nn], h0b[Nn];
  #pragma unroll
  for (int n = 0; n < Nn; ++n) {
    h0a[n] = ALPHAc*xa[n] + HOPW*x1a[n];
    h0b[n] = ALPHAc*xb[n] + HOPW*x1b[n];
  }
  // ---- layer0 hop2 ----
  for (int j = 0; j < Nn; ++j) {
    float aa = 0.f, ab = 0.f;
    #pragma unroll
    for (int i = 0; i < Nn; ++i) {
      float av = an[j*20 + i];
      aa = fmaf(av, x1a[i], aa);
      ab = fmaf(av, x1b[i], ab);
    }
    h0a[j] += HOPW*aa;
    h0b[j] += HOPW*ab;
  }

  // ---- matmul0 (readlane broadcast of h columns) + LN0 ----
  float acc[Nn];
  #pragma unroll
  for (int n = 0; n < Nn; ++n) acc[n] = 0.f;
  {
    const float* w0p = W0 + lane*DIN;
    #pragma unroll
    for (int kb = 0; kb < 64; kb += 16) {
      float w[16];
      #pragma unroll
      for (int q4 = 0; q4 < 4; ++q4)
        *(float4*)&w[4*q4] = *(const float4*)(w0p + kb + 4*q4);
      #pragma unroll
      for (int kk = 0; kk < 16; ++kk) {
        int k = kb + kk;
        #pragma unroll
        for (int n = 0; n < Nn; ++n)
          acc[n] = fmaf(rlanef(h0a[n], k), w[kk], acc[n]);
      }
    }
    float w[16];
    #pragma unroll
    for (int q4 = 0; q4 < 4; ++q4)
      *(float4*)&w[4*q4] = *(const float4*)(w0p + 64 + 4*q4);
    #pragma unroll
    for (int kk = 0; kk < 16; ++kk) {
      #pragma unroll
      for (int n = 0; n < Nn; ++n)
        acc[n] = fmaf(rlanef(h0b[n], kk), w[kk], acc[n]);
    }
  }
  float yv[Nn];
  {
    float bias = b0[lane], gam = g0[lane], bet = be0[lane];
    #pragma unroll
    for (int n = 0; n < Nn; ++n) {
      float v  = acc[n] + bias;
      float mu = wsum(v)*(1.f/64.f);
      float d  = v - mu;
      float var = wsum(d*d)*(1.f/64.f);
      yv[n] = d*rsqrtf(var + LNEPS)*gam + bet;
    }
  }

  // ---- layer1 hops ----
  float x1c[Nn];
  for (int j = 0; j < Nn; ++j) {
    float aa = 0.f;
    #pragma unroll
    for (int i = 0; i < Nn; ++i)
      aa = fmaf(an[j*20 + i], yv[i], aa);
    x1c[j] = aa;
  }
  float h1[Nn];
  #pragma unroll
  for (int n = 0; n < Nn; ++n) h1[n] = ALPHAc*yv[n] + HOPW*x1c[n];
  for (int j = 0; j < Nn; ++j) {
    float aa = 0.f;
    #pragma unroll
    for (int i = 0; i < Nn; ++i)
      aa = fmaf(an[j*20 + i], x1c[i], aa);
    h1[j] += HOPW*aa;
  }

  // ---- matmul1 + residual + LN1 + store ----
  float acc1[Nn];
  #pragma unroll
  for (int n = 0; n < Nn; ++n) acc1[n] = 0.f;
  {
    const float* w1p = W1 + lane*Dd;
    #pragma unroll
    for (int kb = 0; kb < 64; kb += 16) {
      float w[16];
      #pragma unroll
      for (int q4 = 0; q4 < 4; ++q4)
        *(float4*)&w[4*q4] = *(const float4*)(w1p + kb + 4*q4);
      #pragma unroll
      for (int kk = 0; kk < 16; ++kk) {
        int k = kb + kk;
        #pragma unroll
        for (int n = 0; n < Nn; ++n)
          acc1[n] = fmaf(rlanef(h1[n], k), w[kk], acc1[n]);
      }
    }
  }
  {
    float bias = b1[lane], gam = g1[lane], bet = be1[lane];
    float* ob = out + (((size_t)b*Nn)*Tt + t)*Dd + lane;
    #pragma unroll
    for (int n = 0; n < Nn; ++n) {
      float v  = acc1[n] + bias + yv[n];
      float mu = wsum(v)*(1.f/64.f);
      float d  = v - mu;
      float var = wsum(d*d)*(1.f/64.f);
      ob[(size_t)n*Tt*Dd] = d*rsqrtf(var + LNEPS)*gam + bet;
    }
  }
}

// ======================= fallback: monolithic kernel (round-1, known-correct) =======================
__global__ __launch_bounds__(64)
void gcm_mono(
  const float* __restrict__ feat,
  const float* __restrict__ adj,
  const float* __restrict__ ew_p, const float* __restrict__ eb_p,
  const float* __restrict__ W0, const float* __restrict__ b0,
  const float* __restrict__ W1, const float* __restrict__ b1,
  const float* __restrict__ g0, const float* __restrict__ be0,
  const float* __restrict__ g1, const float* __restrict__ be1,
  float* __restrict__ out)
{
  const int g    = blockIdx.x;
  const int lane = threadIdx.x;
  const int b    = g >> 10;
  const int t    = g & (Tt - 1);

  __shared__ float  anS[Nn*Nn];
  __shared__ float  peS[Nn*KE];
  __shared__ double evS[Nn];
  __shared__ float  rsS[Nn];
  __shared__ float  csS[Nn];
  __shared__ __align__(16) char arena[6080];
  double* Ad   = (double*)(arena);
  float*  Vf   = (float*)(arena + 3040);
  float*  adjS = (float*)(arena + 4560);
  float*  hb   = (float*)(arena);

  float xr[Nn];
  const float* fb = feat + (((size_t)b*Nn)*Tt + t)*Dd + lane;
  #pragma unroll
  for (int n = 0; n < Nn; ++n) xr[n] = fb[(size_t)n*Tt*Dd];

  const float ew = ew_p[0], eb = eb_p[0];

  for (int idx = lane; idx < Nn*Nn; idx += 64)
    adjS[idx] = adj[(size_t)g*(Nn*Nn) + idx];
  __syncthreads();

  if (lane < Nn) {
    float rs = 0.f;
    for (int j = 0; j < Nn; ++j) rs += adjS[lane*Nn + j];
    rsS[lane] = rsqrtf(fmaxf(rs, 1e-6f));
  }
  for (int idx = lane; idx < Nn*Nn; idx += 64) {
    int i = idx / Nn, j = idx - i*Nn;
    float a = adjS[idx];
    bool m = a > 0.f;
    float wv = m ? softplusf(a*ew + eb) : ((i == j) ? 1.f : 0.f);
    anS[idx] = wv;
  }
  __syncthreads();
  if (lane < Nn) {
    float cs = 0.f;
    for (int i = 0; i < Nn; ++i) cs += anS[i*Nn + lane];
    csS[lane] = (cs > 0.f) ? rsqrtf(fmaxf(cs, 1e-30f)) : 0.f;
  }
  __syncthreads();
  for (int idx = lane; idx < Nn*Nn; idx += 64) {
    int i = idx / Nn, j = idx - i*Nn;
    anS[idx] = csS[i]*anS[idx]*csS[j];
    float anij = rsS[i]*adjS[i*Nn + j]*rsS[j];
    float anji = rsS[j]*adjS[j*Nn + i]*rsS[i];
    double m = ((i == j) ? (1.0 + 1e-5) : 0.0) - 0.5*((double)anij + (double)anji);
    Ad[i*20 + j] = m;
    Vf[i*20 + j] = (i == j) ? 1.f : 0.f;
  }
  __syncthreads();

  for (int sweep = 0; sweep < 30; ++sweep) {
    double off = 0.0;
    for (int idx = lane; idx < Nn*Nn; idx += 64) {
      int i = idx / Nn, j = idx - i*Nn;
      if (i < j) { double v = Ad[i*20 + j]; off += v*v; }
    }
    #pragma unroll
    for (int o = 32; o > 0; o >>= 1) off += __shfl_xor(off, o, 64);
    if (off < 1e-22) break;
    for (int p = 0; p < Nn - 1; ++p) {
      for (int q = p + 1; q < Nn; ++q) {
        double apq = Ad[p*20 + q];
        if (fabs(apq) > 1e-15) {
          double app = Ad[p*20 + p], aqq = Ad[q*20 + q];
          double tau = (aqq - app) / (2.0*apq);
          double tt  = sqrt(1.0 + tau*tau);
          double tv  = (tau >= 0.0) ? 1.0/(tau + tt) : 1.0/(tau - tt);
          double c   = 1.0/sqrt(1.0 + tv*tv);
          double s   = tv*c;
          double akp = 0.0, akq = 0.0; float vkp = 0.f, vkq = 0.f;
          if (lane < Nn) {
            akp = Ad[lane*20 + p]; akq = Ad[lane*20 + q];
            vkp = Vf[lane*20 + p]; vkq = Vf[lane*20 + q];
          }
          __syncthreads();
          if (lane < Nn) {
            double nkp = c*akp - s*akq;
            double nkq = s*akp + c*akq;
            if (lane == p) {
              nkp = c*c*app - 2.0*c*s*apq + s*s*aqq;
              nkq = 0.0;
            } else if (lane == q) {
              nkp = 0.0;
              nkq = s*s*app + 2.0*c*s*apq + c*c*aqq;
            }
            Ad[lane*20 + p] = nkp; Ad[p*20 + lane] = nkp;
            Ad[lane*20 + q] = nkq; Ad[q*20 + lane] = nkq;
            float fc = (float)c, fs = (float)s;
            Vf[lane*20 + p] = fc*vkp - fs*vkq;
            Vf[lane*20 + q] = fs*vkp + fc*vkq;
          }
          __syncthreads();
        }
      }
    }
  }

  if (lane < Nn) evS[lane] = Ad[lane*20 + lane];
  __syncthreads();
  if (lane < Nn) {
    double lam = evS[lane];
    int r = 0;
    for (int j = 0; j < Nn; ++j) {
      double lj = evS[j];
      r += (lj < lam) || (lj == lam && j < lane);
    }
    if (r < KE) {
      float sacc = 0.f;
      for (int n = 0; n < Nn; ++n) sacc += Vf[n*20 + lane];
      float sgn = (sacc < 0.f) ? -1.f : 1.f;
      for (int n = 0; n < Nn; ++n) peS[n*KE + r] = Vf[n*20 + lane]*sgn;
    }
  }
  __syncthreads();

  {
    float x1[Nn], x2[Nn];
    for (int j = 0; j < Nn; ++j) {
      float a2 = 0.f;
      #pragma unroll
      for (int i = 0; i < Nn; ++i) a2 += anS[i*Nn + j]*xr[i];
      x1[j] = a2;
    }
    for (int j = 0; j < Nn; ++j) {
      float a2 = 0.f;
      #pragma unroll
      for (int i = 0; i < Nn; ++i) a2 += anS[i*Nn + j]*x1[i];
      x2[j] = a2;
    }
    #pragma unroll
    for (int n = 0; n < Nn; ++n)
      hb[n*DIN + lane] = ALPHAc*xr[n] + HOPW*(x1[n] + x2[n]);
  }
  if (lane < KE) {
    float xc[Nn], x1[Nn], x2[Nn];
    #pragma unroll
    for (int n = 0; n < Nn; ++n) xc[n] = peS[n*KE + lane];
    for (int j = 0; j < Nn; ++j) {
      float a2 = 0.f;
      #pragma unroll
      for (int i = 0; i < Nn; ++i) a2 += anS[i*Nn + j]*xc[i];
      x1[j] = a2;
    }
    for (int j = 0; j < Nn; ++j) {
      float a2 = 0.f;
      #pragma unroll
      for (int i = 0; i < Nn; ++i) a2 += anS[i*Nn + j]*x1[i];
      x2[j] = a2;
    }
    #pragma unroll
    for (int n = 0; n < Nn; ++n)
      hb[n*DIN + Dd + lane] = ALPHAc*xc[n] + HOPW*(x1[n] + x2[n]);
  }
  __syncthreads();

  float acc[Nn];
  #pragma unroll
  for (int n = 0; n < Nn; ++n) acc[n] = 0.f;
  {
    const float* w0r = W0 + lane*DIN;
    #pragma unroll 8
    for (int k = 0; k < DIN; ++k) {
      float wv = w0r[k];
      #pragma unroll
      for (int n = 0; n < Nn; ++n) acc[n] += hb[n*DIN + k]*wv;
    }
  }
  float yv[Nn];
  {
    float bias = b0[lane], gam = g0[lane], bet = be0[lane];
    #pragma unroll
    for (int n = 0; n < Nn; ++n) {
      float v  = acc[n] + bias;
      float mu = wsum(v)*(1.f/64.f);
      float d  = v - mu;
      float var = wsum(d*d)*(1.f/64.f);
      yv[n] = d*rsqrtf(var + LNEPS)*gam + bet;
    }
  }

  {
    float x1[Nn], x2[Nn];
    for (int j = 0; j < Nn; ++j) {
      float a2 = 0.f;
      #pragma unroll
      for (int i = 0; i < Nn; ++i) a2 += anS[i*Nn + j]*yv[i];
      x1[j] = a2;
    }
    for (int j = 0; j < Nn; ++j) {
      float a2 = 0.f;
      #pragma unroll
      for (int i = 0; i < Nn; ++i) a2 += anS[i*Nn + j]*x1[i];
      x2[j] = a2;
    }
    __syncthreads();
    #pragma unroll
    for (int n = 0; n < Nn; ++n)
      hb[n*Dd + lane] = ALPHAc*yv[n] + HOPW*(x1[n] + x2[n]);
    __syncthreads();
  }

  float acc1[Nn];
  #pragma unroll
  for (int n = 0; n < Nn; ++n) acc1[n] = 0.f;
  {
    const float* w1r = W1 + lane*Dd;
    #pragma unroll 8
    for (int k = 0; k < Dd; ++k) {
      float wv = w1r[k];
      #pragma unroll
      for (int n = 0; n < Nn; ++n) acc1[n] += hb[n*Dd + k]*wv;
    }
  }
  {
    float bias = b1[lane], gam = g1[lane], bet = be1[lane];
    float* ob = out + (((size_t)b*Nn)*Tt + t)*Dd + lane;
    #pragma unroll
    for (int n = 0; n < Nn; ++n) {
      float v  = acc1[n] + bias + yv[n];
      float mu = wsum(v)*(1.f/64.f);
      float d  = v - mu;
      float var = wsum(d*d)*(1.f/64.f);
      ob[(size_t)n*Tt*Dd] = d*rsqrtf(var + LNEPS)*gam + bet;
    }
  }
}

extern "C" void kernel_launch(void* const* d_in, const int* in_sizes, int n_in,
                              void* d_out, int out_size, void* d_ws, size_t ws_size,
                              hipStream_t stream) {
  (void)in_sizes; (void)n_in; (void)out_size;
  const float* feat = (const float*)d_in[0];
  const float* adj  = (const float*)d_in[1];
  const float* ew   = (const float*)d_in[2];
  const float* eb   = (const float*)d_in[3];
  const float* W0   = (const float*)d_in[4];
  const float* b0   = (const float*)d_in[5];
  const float* W1   = (const float*)d_in[6];
  const float* b1   = (const float*)d_in[7];
  const float* g0   = (const float*)d_in[8];
  const float* be0  = (const float*)d_in[9];
  const float* g1   = (const float*)d_in[10];
  const float* be1  = (const float*)d_in[11];
  float* out = (float*)d_out;

  if (ws_size >= WS_NEED) {
    float* anW = (float*)d_ws;
    float* peW = anW + (size_t)Gg*AN_STRIDE;
    hipLaunchKernelGGL(eig_kernel, dim3(Gg/4), dim3(256), 0, stream,
                       adj, ew, eb, anW, peW);
    hipLaunchKernelGGL(gnn_kernel, dim3(Gg), dim3(64), 0, stream,
                       feat, anW, peW, W0, b0, W1, b1, g0, be0, g1, be1, out);
  } else {
    hipLaunchKernelGGL(gcm_mono, dim3(Gg), dim3(64), 0, stream,
                       feat, adj, ew, eb, W0, b0, W1, b1, g0, be0, g1, be1, out);
  }
}